// Round 3
// baseline (1253.288 us; speedup 1.0000x reference)
//
#include <hip/hip_runtime.h>

#define UNITS 32
#define NB 256
#define NT 1024
#define NUNF 6
#define MAXSLOT 20

typedef const float* fp;

__device__ __forceinline__ float frcp(float x) { return __builtin_amdgcn_rcpf(x); }

// ws layout (bytes):
//   0      : pre[32*MAXSLOT] int            (2560)
//   2560   : ss  [32*MAXSLOT] float         (2560)   a_s = -sigma
//   5120   : nms [32*MAXSLOT] float         (2560)   a_n = sigma*mu
//   7680   : ww  [32*MAXSLOT] float         (2560)
//   10240  : we  [32*MAXSLOT] float         (2560)
//   12800  : maxdeg int                     (4)
//   16384  : vstate [NB*32] float           (32768)
//   49152  : sens  [CT*NB*32] float2        (CT*65536)
#define WS_VSTATE 16384
#define WS_SENS   49152

// ---------------- Kernel 0: padded per-post recurrent synapse lists ----------------
__global__ void build_lists(fp w_syn, fp mu, fp sigma, fp erev, const int* spm,
                            int* pre, float* ss, float* nms, float* ww, float* we, int* maxdeg) {
    __shared__ int degs[32];
    int j = threadIdx.x;
    if (j < 32) {
        int cnt = 0;
        for (int i = 0; i < 32; ++i) {
            int p = i * 32 + j;
            if (spm[p] != 0) {
                int slot = j * MAXSLOT + cnt;
                float s = sigma[p];
                float wv = w_syn[p];
                pre[slot] = i;
                ss[slot] = -s;                 // xg = -sigma*(vp - mu)
                nms[slot] = s * mu[p];
                ww[slot] = wv;
                we[slot] = wv * erev[p];
                ++cnt;
            }
        }
        for (int c = cnt; c < MAXSLOT; ++c) {
            int slot = j * MAXSLOT + c;
            pre[slot] = 0; ss[slot] = 0.f; nms[slot] = 0.f; ww[slot] = 0.f; we[slot] = 0.f;
        }
        degs[j] = cnt;
    }
    __syncthreads();
    if (j == 0) {
        int m = 0;
        for (int k = 0; k < 32; ++k) m = max(m, degs[k]);
        *maxdeg = m;
    }
}

// ---------------- Kernel A: dense stack + sensory gate sums ----------------
__global__ __launch_bounds__(256) void dense_sens(
    fp x, fp d1w, fp d1b, fp d2w, fp d2b, fp iw, fp ib,
    fp sw, fp smu, fp ssg, fp serev, const int* smask,
    float2* sens, int t0, int CT) {
    __shared__ float W1s[256], b1s[128], W2s[4096], b2s[32], iws[32], ibs[32];
    __shared__ float gss[1024], gnm[1024], gwm[1024], gwe[1024];
    __shared__ float hbuf[8][128];
    __shared__ float ibuf[8][32];
    int tid = threadIdx.x;
    if (tid < 256) W1s[tid] = d1w[tid];
    if (tid < 128) b1s[tid] = d1b[tid];
    for (int p = tid; p < 4096; p += 256) W2s[p] = d2w[p];
    if (tid < 32) { b2s[tid] = d2b[tid]; iws[tid] = iw[tid]; ibs[tid] = ib[tid]; }
    for (int p = tid; p < 1024; p += 256) {
        float s = ssg[p];
        float wv = sw[p];
        gss[p] = -s;                      // xg = -s*(inp - mu)
        gnm[p] = s * smu[p];
        gwm[p] = wv * (float)smask[p];
        gwe[p] = wv * serev[p];
    }
    __syncthreads();
    int g = tid >> 5, j = tid & 31;
    const float2* x2 = (const float2*)x;
    int niters = CT * 32;                 // 8 gids per block-iteration
    for (int itg = blockIdx.x; itg < niters; itg += gridDim.x) {
        int cg = itg * 8 + g;             // cg = lt*256 + b
        int lt = cg >> 8, b = cg & 255;
        int t = t0 + lt;
        float2 xv = x2[b * NT + t];
#pragma unroll
        for (int r = 0; r < 4; ++r) {
            int k = j + 32 * r;
            float hk = fmaf(xv.y, W1s[128 + k], fmaf(xv.x, W1s[k], b1s[k]));
            hbuf[g][k] = hk > 0.f ? hk : 0.f;
        }
        float acc = b2s[j];
#pragma unroll 8
        for (int k = 0; k < 128; ++k) acc = fmaf(hbuf[g][k], W2s[k * 32 + j], acc);
        ibuf[g][j] = fmaf(acc, iws[j], ibs[j]);
        float wn = 0.f, wd = 0.f;
        for (int i = 0; i < 32; ++i) {
            int p = i * 32 + j;
            float xg = fmaf(ibuf[g][i], gss[p], gnm[p]);
            float sg = frcp(1.f + __expf(xg));
            wn = fmaf(gwe[p], sg, wn);
            wd = fmaf(gwm[p], sg, wd);
        }
        sens[cg * 32 + j] = make_float2(wn, wd);
    }
}

// ---------------- Kernel B: sequential LTC scan (lane=unit, half-wave=batch) ----------------
template <int M>
__device__ void scan_impl(const float2* __restrict__ sens, fp gleak, fp vleak, fp cm,
                          const int* pre, const float* ss, const float* nms,
                          const float* ww, const float* we, fp ow, fp ob,
                          float* vstate, int t0, int CT, float* out) {
    int lane = threadIdx.x;
    int j = lane & 31;
    int b = blockIdx.x * 2 + (lane >> 5);
    float cm_t = cm[j] * (float)NUNF;
    float gl = gleak[j];
    float glvl = gl * vleak[j];
    float cden = cm_t + gl + 1e-8f;
    int ap[M];
    float a_s[M], a_n[M], a_w[M], a_e[M];
#pragma unroll
    for (int s = 0; s < M; ++s) {
        int slot = j * MAXSLOT + s;
        ap[s] = ((lane & 32) | pre[slot]) << 2;   // ds_bpermute byte address
        a_s[s] = ss[slot]; a_n[s] = nms[slot];
        a_w[s] = ww[slot]; a_e[s] = we[slot];
    }
    float v = (t0 == 0) ? 0.f : vstate[b * 32 + j];
    const float2* sp = sens + b * 32 + j;
    float2 cur = sp[0];
    for (int t = 0; t < CT; ++t) {
        float2 nxt = (t + 1 < CT) ? sp[(size_t)(t + 1) * (NB * 32)] : make_float2(0.f, 0.f);
#pragma unroll
        for (int u = 0; u < NUNF; ++u) {
            float vp[M];
#pragma unroll
            for (int s = 0; s < M; ++s)
                vp[s] = __int_as_float(__builtin_amdgcn_ds_bpermute(ap[s], __float_as_int(v)));
            float wn = cur.x, wd = cur.y;
#pragma unroll
            for (int s = 0; s < M; ++s) {
                float xg = fmaf(a_s[s], vp[s], a_n[s]);
                float sg = frcp(1.f + __expf(xg));
                wn = fmaf(a_e[s], sg, wn);
                wd = fmaf(a_w[s], sg, wd);
            }
            v = fmaf(cm_t, v, glvl + wn) * frcp(cden + wd);
        }
        cur = nxt;
    }
    vstate[b * 32 + j] = v;
    if (t0 + CT == NT && j == 0)
        out[b] = fmaf(v, ow[0], ob[0]);
}

__global__ __launch_bounds__(64) void scan_kernel(
    const float2* __restrict__ sens, fp gleak, fp vleak, fp cm,
    const int* pre, const float* ss, const float* nms, const float* ww, const float* we,
    fp ow, fp ob, const int* maxdeg, float* vstate, int t0, int CT, float* out) {
    int md = *maxdeg;
    if (md <= 4)       scan_impl<4>(sens, gleak, vleak, cm, pre, ss, nms, ww, we, ow, ob, vstate, t0, CT, out);
    else if (md <= 6)  scan_impl<6>(sens, gleak, vleak, cm, pre, ss, nms, ww, we, ow, ob, vstate, t0, CT, out);
    else if (md <= 8)  scan_impl<8>(sens, gleak, vleak, cm, pre, ss, nms, ww, we, ow, ob, vstate, t0, CT, out);
    else if (md <= 12) scan_impl<12>(sens, gleak, vleak, cm, pre, ss, nms, ww, we, ow, ob, vstate, t0, CT, out);
    else               scan_impl<18>(sens, gleak, vleak, cm, pre, ss, nms, ww, we, ow, ob, vstate, t0, CT, out);
}

extern "C" void kernel_launch(void* const* d_in, const int* in_sizes, int n_in,
                              void* d_out, int out_size, void* d_ws, size_t ws_size,
                              hipStream_t stream) {
    fp x     = (fp)d_in[0];
    fp d1w   = (fp)d_in[1];
    fp d1b   = (fp)d_in[2];
    fp d2w   = (fp)d_in[3];
    fp d2b   = (fp)d_in[4];
    fp iw    = (fp)d_in[5];
    fp ib    = (fp)d_in[6];
    fp ow    = (fp)d_in[7];
    fp ob    = (fp)d_in[8];
    fp gleak = (fp)d_in[9];
    fp vleak = (fp)d_in[10];
    fp cm    = (fp)d_in[11];
    fp wsyn  = (fp)d_in[12];
    fp mu    = (fp)d_in[13];
    fp sigma = (fp)d_in[14];
    fp erev  = (fp)d_in[15];
    fp sw    = (fp)d_in[16];
    fp smu   = (fp)d_in[17];
    fp ssg   = (fp)d_in[18];
    fp serev = (fp)d_in[19];
    const int* spm   = (const int*)d_in[20];
    const int* smask = (const int*)d_in[21];

    char* wsb = (char*)d_ws;
    int*   pre    = (int*)  (wsb + 0);
    float* ss     = (float*)(wsb + 2560);
    float* nms    = (float*)(wsb + 5120);
    float* ww     = (float*)(wsb + 7680);
    float* we     = (float*)(wsb + 10240);
    int*   maxdeg = (int*)  (wsb + 12800);
    float* vstate = (float*)(wsb + WS_VSTATE);
    float2* sens  = (float2*)(wsb + WS_SENS);

    // largest power-of-two timestep chunk whose sens staging fits ws
    size_t per_t = (size_t)NB * 32 * sizeof(float2);          // 65536 B
    int CT = 1;
    if (ws_size > WS_SENS) {
        size_t m = (ws_size - WS_SENS) / per_t;
        int ct = 1;
        while (ct < 1024 && (size_t)(ct * 2) <= m) ct *= 2;
        if (m >= 1) CT = ct;
    }

    build_lists<<<1, 64, 0, stream>>>(wsyn, mu, sigma, erev, spm, pre, ss, nms, ww, we, maxdeg);

    int nch = NT / CT;
    for (int c = 0; c < nch; ++c) {
        int t0 = c * CT;
        int blocks = CT * 32; if (blocks > 1024) blocks = 1024;
        dense_sens<<<blocks, 256, 0, stream>>>(x, d1w, d1b, d2w, d2b, iw, ib,
                                               sw, smu, ssg, serev, smask, sens, t0, CT);
        scan_kernel<<<NB / 2, 64, 0, stream>>>(sens, gleak, vleak, cm, pre, ss, nms, ww, we,
                                               ow, ob, maxdeg, vstate, t0, CT, (float*)d_out);
    }
}